// Round 4
// baseline (14500.336 us; speedup 1.0000x reference)
//
#include <hip/hip_runtime.h>
#include <math.h>

#define CDIM 128
#define DDIM 32
#define TB 32   // edges per tile in k_agg

static __device__ __forceinline__ float lrelu(float v) { return v >= 0.f ? v : 0.01f * v; }
static __device__ __forceinline__ float sigm(float x) {
    return __builtin_amdgcn_rcpf(1.f + __expf(-x));
}
static __device__ __forceinline__ float softp(float x) {
    // stable softplus: max(x,0) + log(1+exp(-|x|))
    return fmaxf(x, 0.f) + __logf(1.f + __expf(-fabsf(x)));
}

// ---------------- CSR build (counting sort by dst) ----------------
__global__ void k_hist(const int* __restrict__ ei, int* __restrict__ counts, int E) {
    int stride = gridDim.x * blockDim.x;
    for (int e = blockIdx.x * blockDim.x + threadIdx.x; e < E; e += stride)
        atomicAdd(&counts[ei[E + e]], 1);  // dst = row 1
}

__global__ void k_scan1(const int* __restrict__ counts, int* __restrict__ excl,
                        int* __restrict__ bsum, int N) {
    __shared__ int sm[256];
    int t = threadIdx.x, idx = blockIdx.x * 256 + t;
    int v = (idx < N) ? counts[idx] : 0;
    sm[t] = v; __syncthreads();
    for (int off = 1; off < 256; off <<= 1) {
        int x = (t >= off) ? sm[t - off] : 0;
        __syncthreads();
        sm[t] += x;
        __syncthreads();
    }
    if (idx < N) excl[idx] = sm[t] - v;
    if (t == 255) bsum[blockIdx.x] = sm[255];
}

__global__ void k_scan2(const int* __restrict__ bsum, int* __restrict__ boff,
                        int* __restrict__ rowptr_end, int NB) {
    __shared__ int sm[256];
    int t = threadIdx.x;
    int v = (t < NB) ? bsum[t] : 0;
    sm[t] = v; __syncthreads();
    for (int off = 1; off < 256; off <<= 1) {
        int x = (t >= off) ? sm[t - off] : 0;
        __syncthreads();
        sm[t] += x;
        __syncthreads();
    }
    if (t < NB) boff[t] = sm[t] - v;
    if (t == 255) *rowptr_end = sm[255];  // == E
}

__global__ void k_scan3(int* __restrict__ rowptr, int* __restrict__ cur,
                        const int* __restrict__ boff, int N) {
    int idx = blockIdx.x * blockDim.x + threadIdx.x;
    if (idx < N) {
        int v = rowptr[idx] + boff[idx >> 8];
        rowptr[idx] = v;
        cur[idx] = v;
    }
}

__global__ void k_fill(const int* __restrict__ ei, int* __restrict__ cur,
                       int* __restrict__ src_s, int* __restrict__ dst_s,
                       int* __restrict__ eid_s, int E) {
    int stride = gridDim.x * blockDim.x;
    for (int e = blockIdx.x * blockDim.x + threadIdx.x; e < E; e += stride) {
        int d = ei[E + e];
        int pos = atomicAdd(&cur[d], 1);
        src_s[pos] = ei[e];   // src = row 0
        dst_s[pos] = d;
        eid_s[pos] = e;
    }
}

// ---------------- weight transpose: W_edge [32][128] -> [128][32] ----------------
__global__ void k_wt(const float* __restrict__ Wf1, const float* __restrict__ Ws1,
                     const float* __restrict__ Wf2, const float* __restrict__ Ws2,
                     float* __restrict__ WfT1, float* __restrict__ WsT1,
                     float* __restrict__ WfT2, float* __restrict__ WsT2) {
    int t = blockIdx.x * blockDim.x + threadIdx.x;
    if (t < DDIM * CDIM) {
        int c = t >> 5, d = t & 31;
        int src = d * CDIM + c;
        WfT1[t] = Wf1[src];
        WsT1[t] = Ws1[src];
        WfT2[t] = Wf2[src];
        WsT2[t] = Ws2[src];
    }
}

// ---------------- layer 1: h0 = leaky([x, onehot] @ lin_W + b) ----------------
template <int ROWS>
__global__ void k_lin1(const float* __restrict__ x, const int* __restrict__ y,
                       const int* __restrict__ batch, const float* __restrict__ W,
                       const float* __restrict__ b, float* __restrict__ h0, int N) {
    __shared__ float xs[ROWS][CDIM];
    int c = threadIdx.x;             // 128 threads
    int n0 = blockIdx.x * ROWS;
    for (int r = 0; r < ROWS; r++) xs[r][c] = x[(n0 + r) * CDIM + c];
    __syncthreads();
    float acc[ROWS];
#pragma unroll
    for (int r = 0; r < ROWS; r++) {
        int cls = y[batch[n0 + r]];
        acc[r] = b[c] + W[(CDIM + cls) * CDIM + c];  // one-hot row select
    }
    for (int k = 0; k < CDIM; k++) {
        float w = W[k * CDIM + c];
#pragma unroll
        for (int r = 0; r < ROWS; r++) acc[r] = fmaf(xs[r][k], w, acc[r]);
    }
    for (int r = 0; r < ROWS; r++) h0[(n0 + r) * CDIM + c] = lrelu(acc[r]);
}

// ---- per-conv node GEMMs: PR[n][c]={h@Wf_d+bf, h@Ws_d+bs}, QS[n][c]={h@Wf_s, h@Ws_s} ----
template <int ROWS>
__global__ void k_gemm4(const float* __restrict__ h, const float* __restrict__ Wf,
                        const float* __restrict__ Ws, const float* __restrict__ bf,
                        const float* __restrict__ bs, float2* __restrict__ PR,
                        float2* __restrict__ QS, int N) {
    __shared__ float hs[ROWS][CDIM];
    int c = threadIdx.x;
    int n0 = blockIdx.x * ROWS;
    for (int r = 0; r < ROWS; r++) hs[r][c] = h[(n0 + r) * CDIM + c];
    __syncthreads();
    float ap[ROWS], aq[ROWS], ar[ROWS], asv[ROWS];
    float vbf = bf[c], vbs = bs[c];
#pragma unroll
    for (int r = 0; r < ROWS; r++) { ap[r] = vbf; aq[r] = 0.f; ar[r] = vbs; asv[r] = 0.f; }
    for (int k = 0; k < CDIM; k++) {
        float wp = Wf[k * CDIM + c];
        float wq = Wf[(CDIM + k) * CDIM + c];
        float wr = Ws[k * CDIM + c];
        float wsv = Ws[(CDIM + k) * CDIM + c];
#pragma unroll
        for (int r = 0; r < ROWS; r++) {
            float hv = hs[r][k];
            ap[r] = fmaf(hv, wp, ap[r]);
            aq[r] = fmaf(hv, wq, aq[r]);
            ar[r] = fmaf(hv, wr, ar[r]);
            asv[r] = fmaf(hv, wsv, asv[r]);
        }
    }
    for (int r = 0; r < ROWS; r++) {
        int o = (n0 + r) * CDIM + c;
        PR[o] = make_float2(ap[r], ar[r]);
        QS[o] = make_float2(aq[r], asv[r]);
    }
}

// ---------------- edge aggregation: flat 32-edge tiles, register accumulators ----------------
// outb must be prefilled with the residual h; per-dst partial sums are atomicAdd'ed at
// sorted-run boundaries (~1.5 atomics per output element).
__launch_bounds__(128, 2)
__global__ void k_agg(const float2* __restrict__ QS, const float2* __restrict__ PR,
                      const float* __restrict__ eattr, const float* __restrict__ WfT,
                      const float* __restrict__ WsT, const int* __restrict__ src_s,
                      const int* __restrict__ dst_s, const int* __restrict__ eid_s,
                      float* __restrict__ outb, int E) {
    const int c = threadIdx.x;  // 128 threads, one channel each
    __shared__ float4 se4[TB][8];
    __shared__ int ss[TB], sd[TB];
    __shared__ unsigned int smask;
    const int base = blockIdx.x * TB;

    // ---- stage indices + boundary mask (wave 0, lanes 0..31) ----
    bool flag = false;
    if (c < TB) {
        int e = base + c;
        bool inb = (e < E);
        int ec = inb ? e : (E - 1);
        ss[c] = inb ? src_s[ec] : 0;
        sd[c] = inb ? dst_s[ec] : 0;
        flag = inb && ((e == E - 1) || (c == TB - 1) || (dst_s[e] != dst_s[e + 1]));
    }
    unsigned long long b = __ballot(flag);
    if (c == 0) smask = (unsigned int)b;
    // ---- stage edge_attr tile: 256 float4 slots, 2 per thread ----
    {
        int s0 = c, s1 = c + 128;
        int j0 = s0 >> 3, d40 = s0 & 7;
        int j1 = s1 >> 3, d41 = s1 & 7;
        int e0 = (base + j0 < E) ? eid_s[base + j0] : 0;
        int e1 = (base + j1 < E) ? eid_s[base + j1] : 0;
        se4[j0][d40] = *reinterpret_cast<const float4*>(&eattr[(size_t)e0 * DDIM + d40 * 4]);
        se4[j1][d41] = *reinterpret_cast<const float4*>(&eattr[(size_t)e1 * DDIM + d41 * 4]);
    }
    __syncthreads();

    // ---- init accumulators with the node-GEMM parts (P+Q, R+S) ----
    float xf[TB], xs[TB];
#pragma unroll
    for (int j = 0; j < TB; j++) {
        float2 qs = QS[(size_t)ss[j] * CDIM + c];
        float2 pr = PR[(size_t)sd[j] * CDIM + c];
        xf[j] = qs.x + pr.x;
        xs[j] = qs.y + pr.y;
    }
    // ---- edge-attr dot: rank-32 added across all 32 edges; weights reloaded per d-block ----
#pragma unroll
    for (int db = 0; db < 8; db++) {
        float4 wf4 = *reinterpret_cast<const float4*>(&WfT[c * DDIM + db * 4]);
        float4 ws4 = *reinterpret_cast<const float4*>(&WsT[c * DDIM + db * 4]);
#pragma unroll
        for (int j = 0; j < TB; j++) {
            float4 ev = se4[j][db];
            xf[j] = fmaf(ev.x, wf4.x, xf[j]);
            xf[j] = fmaf(ev.y, wf4.y, xf[j]);
            xf[j] = fmaf(ev.z, wf4.z, xf[j]);
            xf[j] = fmaf(ev.w, wf4.w, xf[j]);
            xs[j] = fmaf(ev.x, ws4.x, xs[j]);
            xs[j] = fmaf(ev.y, ws4.y, xs[j]);
            xs[j] = fmaf(ev.z, ws4.z, xs[j]);
            xs[j] = fmaf(ev.w, ws4.w, xs[j]);
        }
    }
    // ---- gates + segmented flush (mask is wave-uniform -> scalar branches) ----
    unsigned int mv = smask;
    unsigned int m = (unsigned int)__builtin_amdgcn_readfirstlane((int)mv);
    float acc = 0.f;
#pragma unroll
    for (int j = 0; j < TB; j++) {
        acc = fmaf(sigm(xf[j]), softp(xs[j]), acc);
        if (m & (1u << j)) {
            atomicAdd(&outb[(size_t)sd[j] * CDIM + c], acc);
            acc = 0.f;
        }
    }
}

// ---------------- leaky relu in place ----------------
__global__ void k_leaky(float4* __restrict__ h, int total4) {
    int stride = gridDim.x * blockDim.x;
    for (int i = blockIdx.x * blockDim.x + threadIdx.x; i < total4; i += stride) {
        float4 v = h[i];
        v.x = lrelu(v.x); v.y = lrelu(v.y); v.z = lrelu(v.z); v.w = lrelu(v.w);
        h[i] = v;
    }
}

// ---------------- group boundaries (batch sorted) ----------------
__global__ void k_gbound(const int* __restrict__ batch, int* __restrict__ gstart,
                         int N, int G) {
    int g = threadIdx.x;
    if (g > G) return;
    int lo = 0, hi = N;
    while (lo < hi) {
        int mid = (lo + hi) >> 1;
        if (batch[mid] < g) lo = mid + 1; else hi = mid;
    }
    gstart[g] = lo;
}

// ---------------- fused mean-pool + MLP head ----------------
__global__ void k_poolhead(const float* __restrict__ h2, const int* __restrict__ gstart,
                           const int* __restrict__ y, const float* __restrict__ fc1W,
                           const float* __restrict__ fc1b, const float* __restrict__ fc2W,
                           const float* __restrict__ fc2b, float* __restrict__ out) {
    __shared__ float pooled[CDIM];
    int g = blockIdx.x;
    int c = threadIdx.x;  // 128 threads
    int n0 = gstart[g], n1 = gstart[g + 1];
    float acc = 0.f;
    for (int n = n0; n < n1; n++) acc += h2[(size_t)n * CDIM + c];
    float inv = 1.f / fmaxf((float)(n1 - n0), 1.f);
    pooled[c] = acc * inv;
    __syncthreads();
    float t = 0.f;
    if (c < 32) {
        t = fc1b[c];
        if (n1 > n0) t += fc1W[(CDIM + y[g]) * 32 + c];  // one-hot part of pooled
        for (int k = 0; k < CDIM; k++) t = fmaf(pooled[k], fc1W[k * 32 + c], t);
        t = lrelu(t) * fc2W[c];
    }
#pragma unroll
    for (int off = 16; off > 0; off >>= 1) t += __shfl_down(t, off, 64);
    if (c == 0) out[g] = sigm(t + fc2b[0]);
}

// ---------------- launch ----------------
extern "C" void kernel_launch(void* const* d_in, const int* in_sizes, int n_in,
                              void* d_out, int out_size, void* d_ws, size_t ws_size,
                              hipStream_t stream) {
    const float* x = (const float*)d_in[0];
    const int* y = (const int*)d_in[1];
    const int* ei = (const int*)d_in[2];
    const float* eattr = (const float*)d_in[3];
    const int* batch = (const int*)d_in[4];
    const float* lin_W = (const float*)d_in[5];
    const float* lin_b = (const float*)d_in[6];
    const float* c1_Wf = (const float*)d_in[7];
    const float* c1_bf = (const float*)d_in[8];
    const float* c1_Ws = (const float*)d_in[9];
    const float* c1_bs = (const float*)d_in[10];
    const float* c2_Wf = (const float*)d_in[11];
    const float* c2_bf = (const float*)d_in[12];
    const float* c2_Ws = (const float*)d_in[13];
    const float* c2_bs = (const float*)d_in[14];
    const float* fc1_W = (const float*)d_in[15];
    const float* fc1_b = (const float*)d_in[16];
    const float* fc2_W = (const float*)d_in[17];
    const float* fc2_b = (const float*)d_in[18];
    float* out = (float*)d_out;

    const int N = in_sizes[0] / CDIM;   // 50000
    const int E = in_sizes[2] / 2;      // 800000
    const int G = in_sizes[1];          // 64
    const int NB = (N + 255) / 256;
    const int NT = (E + TB - 1) / TB;   // 25000 edge tiles

    // workspace carve-up (256B aligned)
    char* ws = (char*)d_ws;
    size_t off = 0;
    auto alloc = [&](size_t bytes) {
        size_t p = off;
        off = (off + bytes + 255) & ~(size_t)255;
        return (void*)(ws + p);
    };
    float* h0 = (float*)alloc((size_t)N * CDIM * 4);   // also final conv2 output
    float* h1 = (float*)alloc((size_t)N * CDIM * 4);
    float2* PR = (float2*)alloc((size_t)N * CDIM * 8);
    float2* QS = (float2*)alloc((size_t)N * CDIM * 8);
    int* rowptr = (int*)alloc((size_t)(N + 1) * 4);
    int* counts = (int*)alloc((size_t)N * 4);
    int* cur = (int*)alloc((size_t)N * 4);
    int* bsum = (int*)alloc((size_t)NB * 4);
    int* boff = (int*)alloc((size_t)NB * 4);
    int* src_s = (int*)alloc((size_t)E * 4);
    int* dst_s = (int*)alloc((size_t)E * 4);
    int* eid_s = (int*)alloc((size_t)E * 4);
    int* gstart = (int*)alloc((size_t)(G + 1) * 4);
    float* WfT1 = (float*)alloc((size_t)DDIM * CDIM * 4);
    float* WsT1 = (float*)alloc((size_t)DDIM * CDIM * 4);
    float* WfT2 = (float*)alloc((size_t)DDIM * CDIM * 4);
    float* WsT2 = (float*)alloc((size_t)DDIM * CDIM * 4);

    hipMemsetAsync(counts, 0, (size_t)N * 4, stream);

    // CSR (counting sort by dst)
    k_hist<<<4096, 256, 0, stream>>>(ei, counts, E);
    k_scan1<<<NB, 256, 0, stream>>>(counts, rowptr, bsum, N);
    k_scan2<<<1, 256, 0, stream>>>(bsum, boff, rowptr + N, NB);
    k_scan3<<<(N + 255) / 256, 256, 0, stream>>>(rowptr, cur, boff, N);
    k_fill<<<4096, 256, 0, stream>>>(ei, cur, src_s, dst_s, eid_s, E);
    k_gbound<<<1, 128, 0, stream>>>(batch, gstart, N, G);
    k_wt<<<(DDIM * CDIM + 255) / 256, 256, 0, stream>>>(
        c1_Wf + 2 * CDIM * CDIM, c1_Ws + 2 * CDIM * CDIM,
        c2_Wf + 2 * CDIM * CDIM, c2_Ws + 2 * CDIM * CDIM, WfT1, WsT1, WfT2, WsT2);

    // layer 1
    k_lin1<16><<<N / 16, CDIM, 0, stream>>>(x, y, batch, lin_W, lin_b, h0, N);

    // conv1: h1 = leaky(h0 + agg1)
    k_gemm4<16><<<N / 16, CDIM, 0, stream>>>(h0, c1_Wf, c1_Ws, c1_bf, c1_bs, PR, QS, N);
    hipMemcpyAsync(h1, h0, (size_t)N * CDIM * 4, hipMemcpyDeviceToDevice, stream);
    k_agg<<<NT, CDIM, 0, stream>>>(QS, PR, eattr, WfT1, WsT1, src_s, dst_s, eid_s, h1, E);
    k_leaky<<<2048, 256, 0, stream>>>((float4*)h1, N * CDIM / 4);

    // conv2: h2 = h1 + agg2 (into h0 buffer)
    k_gemm4<16><<<N / 16, CDIM, 0, stream>>>(h1, c2_Wf, c2_Ws, c2_bf, c2_bs, PR, QS, N);
    hipMemcpyAsync(h0, h1, (size_t)N * CDIM * 4, hipMemcpyDeviceToDevice, stream);
    k_agg<<<NT, CDIM, 0, stream>>>(QS, PR, eattr, WfT2, WsT2, src_s, dst_s, eid_s, h0, E);

    // pool + head
    k_poolhead<<<G, CDIM, 0, stream>>>(h0, gstart, y, fc1_W, fc1_b, fc2_W, fc2_b, out);
}

// Round 6
// 4583.553 us; speedup vs baseline: 3.1636x; 3.1636x over previous
//
#include <hip/hip_runtime.h>
#include <math.h>

#define CDIM 128
#define DDIM 32

static __device__ __forceinline__ float lrelu(float v) { return v >= 0.f ? v : 0.01f * v; }
static __device__ __forceinline__ float sigm(float x) {
    return __builtin_amdgcn_rcpf(1.f + __expf(-x));
}
static __device__ __forceinline__ float softp(float x) {
    // stable softplus: max(x,0) + log(1+exp(-|x|))
    return fmaxf(x, 0.f) + __logf(1.f + __expf(-fabsf(x)));
}

// ---------------- CSR build (counting sort by dst) ----------------
__global__ void k_hist(const int* __restrict__ ei, int* __restrict__ counts, int E) {
    int stride = gridDim.x * blockDim.x;
    for (int e = blockIdx.x * blockDim.x + threadIdx.x; e < E; e += stride)
        atomicAdd(&counts[ei[E + e]], 1);  // dst = row 1
}

__global__ void k_scan1(const int* __restrict__ counts, int* __restrict__ excl,
                        int* __restrict__ bsum, int N) {
    __shared__ int sm[256];
    int t = threadIdx.x, idx = blockIdx.x * 256 + t;
    int v = (idx < N) ? counts[idx] : 0;
    sm[t] = v; __syncthreads();
    for (int off = 1; off < 256; off <<= 1) {
        int x = (t >= off) ? sm[t - off] : 0;
        __syncthreads();
        sm[t] += x;
        __syncthreads();
    }
    if (idx < N) excl[idx] = sm[t] - v;
    if (t == 255) bsum[blockIdx.x] = sm[255];
}

__global__ void k_scan2(const int* __restrict__ bsum, int* __restrict__ boff,
                        int* __restrict__ rowptr_end, int NB) {
    __shared__ int sm[256];
    int t = threadIdx.x;
    int v = (t < NB) ? bsum[t] : 0;
    sm[t] = v; __syncthreads();
    for (int off = 1; off < 256; off <<= 1) {
        int x = (t >= off) ? sm[t - off] : 0;
        __syncthreads();
        sm[t] += x;
        __syncthreads();
    }
    if (t < NB) boff[t] = sm[t] - v;
    if (t == 255) *rowptr_end = sm[255];  // == E
}

__global__ void k_scan3(int* __restrict__ rowptr, int* __restrict__ cur,
                        const int* __restrict__ boff, int N) {
    int idx = blockIdx.x * blockDim.x + threadIdx.x;
    if (idx < N) {
        int v = rowptr[idx] + boff[idx >> 8];
        rowptr[idx] = v;
        cur[idx] = v;
    }
}

__global__ void k_fill(const int* __restrict__ ei, int* __restrict__ cur,
                       int* __restrict__ src_s, int* __restrict__ eid_s, int E) {
    int stride = gridDim.x * blockDim.x;
    for (int e = blockIdx.x * blockDim.x + threadIdx.x; e < E; e += stride) {
        int d = ei[E + e];
        int pos = atomicAdd(&cur[d], 1);
        src_s[pos] = ei[e];   // src = row 0
        eid_s[pos] = e;
    }
}

// ---------------- weight transposes ----------------
// conv W [288][128] -> dstT [128][128], srcT [128][128], edgeT [128][32]
__global__ void k_wtc(const float* __restrict__ Wf, const float* __restrict__ Ws,
                      float* __restrict__ WfdT, float* __restrict__ WfsT,
                      float* __restrict__ WfeT, float* __restrict__ WsdT,
                      float* __restrict__ WssT, float* __restrict__ WseT) {
    int t = blockIdx.x * blockDim.x + threadIdx.x;
    if (t >= 288 * CDIM) return;
    int k = t >> 7, c = t & 127;
    float vf = Wf[t], vs = Ws[t];
    if (k < 128) { WfdT[c * 128 + k] = vf; WsdT[c * 128 + k] = vs; }
    else if (k < 256) { WfsT[c * 128 + k - 128] = vf; WssT[c * 128 + k - 128] = vs; }
    else { WfeT[c * 32 + k - 256] = vf; WseT[c * 32 + k - 256] = vs; }
}

// lin_W first 128 rows -> [128][128] transposed
__global__ void k_wtl(const float* __restrict__ W, float* __restrict__ WT) {
    int t = blockIdx.x * blockDim.x + threadIdx.x;
    if (t >= CDIM * CDIM) return;
    int k = t >> 7, c = t & 127;
    WT[c * 128 + k] = W[t];
}

// ---------------- layer 1: h0 = leaky([x, onehot] @ lin_W + b) ----------------
template <int ROWS>
__global__ void k_lin1(const float* __restrict__ x, const int* __restrict__ y,
                       const int* __restrict__ batch, const float4* __restrict__ WT4,
                       const float* __restrict__ Wfull, const float* __restrict__ b,
                       float* __restrict__ h0, int N) {
    __shared__ float xs_[ROWS][CDIM];
    int c = threadIdx.x;             // 128 threads
    int n0 = blockIdx.x * ROWS;
    for (int r = 0; r < ROWS; r++) {
        int n = n0 + r;
        xs_[r][c] = (n < N) ? x[(size_t)n * CDIM + c] : 0.f;
    }
    __syncthreads();
    float acc[ROWS];
    float vb = b[c];
#pragma unroll
    for (int r = 0; r < ROWS; r++) {
        int n = n0 + r < N ? n0 + r : N - 1;
        int cls = y[batch[n]];
        acc[r] = vb + Wfull[(CDIM + cls) * CDIM + c];  // one-hot row select
    }
    for (int k4 = 0; k4 < CDIM / 4; k4++) {
        float4 w = WT4[c * (CDIM / 4) + k4];
#pragma unroll
        for (int r = 0; r < ROWS; r++) {
            float4 hv = reinterpret_cast<const float4*>(xs_[r])[k4];
            acc[r] = fmaf(hv.x, w.x, acc[r]);
            acc[r] = fmaf(hv.y, w.y, acc[r]);
            acc[r] = fmaf(hv.z, w.z, acc[r]);
            acc[r] = fmaf(hv.w, w.w, acc[r]);
        }
    }
    for (int r = 0; r < ROWS; r++)
        if (n0 + r < N) h0[(size_t)(n0 + r) * CDIM + c] = lrelu(acc[r]);
}

// ---- per-conv node GEMMs: PR[n][c]={h@Wf_d+bf, h@Ws_d+bs}, QS[n][c]={h@Wf_s, h@Ws_s} ----
template <int ROWS>
__global__ void k_gemm4(const float* __restrict__ h, const float4* __restrict__ WfdT4,
                        const float4* __restrict__ WfsT4, const float4* __restrict__ WsdT4,
                        const float4* __restrict__ WssT4, const float* __restrict__ bf,
                        const float* __restrict__ bs, float2* __restrict__ PR,
                        float2* __restrict__ QS, int N) {
    __shared__ float hs[ROWS][CDIM];
    int c = threadIdx.x;
    int n0 = blockIdx.x * ROWS;
    for (int r = 0; r < ROWS; r++) hs[r][c] = h[(size_t)(n0 + r) * CDIM + c];
    __syncthreads();
    float ap[ROWS], aq[ROWS], ar[ROWS], asv[ROWS];
    float vbf = bf[c], vbs = bs[c];
#pragma unroll
    for (int r = 0; r < ROWS; r++) { ap[r] = vbf; aq[r] = 0.f; ar[r] = vbs; asv[r] = 0.f; }
    for (int k4 = 0; k4 < CDIM / 4; k4++) {
        float4 wp = WfdT4[c * (CDIM / 4) + k4];
        float4 wq = WfsT4[c * (CDIM / 4) + k4];
        float4 wr = WsdT4[c * (CDIM / 4) + k4];
        float4 wv = WssT4[c * (CDIM / 4) + k4];
#pragma unroll
        for (int r = 0; r < ROWS; r++) {
            float4 hv = reinterpret_cast<const float4*>(hs[r])[k4];
            ap[r] = fmaf(hv.x, wp.x, ap[r]); ap[r] = fmaf(hv.y, wp.y, ap[r]);
            ap[r] = fmaf(hv.z, wp.z, ap[r]); ap[r] = fmaf(hv.w, wp.w, ap[r]);
            aq[r] = fmaf(hv.x, wq.x, aq[r]); aq[r] = fmaf(hv.y, wq.y, aq[r]);
            aq[r] = fmaf(hv.z, wq.z, aq[r]); aq[r] = fmaf(hv.w, wq.w, aq[r]);
            ar[r] = fmaf(hv.x, wr.x, ar[r]); ar[r] = fmaf(hv.y, wr.y, ar[r]);
            ar[r] = fmaf(hv.z, wr.z, ar[r]); ar[r] = fmaf(hv.w, wr.w, ar[r]);
            asv[r] = fmaf(hv.x, wv.x, asv[r]); asv[r] = fmaf(hv.y, wv.y, asv[r]);
            asv[r] = fmaf(hv.z, wv.z, asv[r]); asv[r] = fmaf(hv.w, wv.w, asv[r]);
        }
    }
    for (int r = 0; r < ROWS; r++) {
        size_t o = (size_t)(n0 + r) * CDIM + c;
        PR[o] = make_float2(ap[r], ar[r]);
        QS[o] = make_float2(aq[r], asv[r]);
    }
}

// ------- edge aggregation: per-node CSR, pinned reg weights, 4-edge dbuf LDS tiles -------
template <int LEAKY>
__launch_bounds__(128, 3)
__global__ void k_agg(const float* __restrict__ h, const float2* __restrict__ PR,
                      const float2* __restrict__ QS, const float* __restrict__ eattr,
                      const float* __restrict__ WfeT, const float* __restrict__ WseT,
                      const int* __restrict__ rowptr, const int* __restrict__ src_s,
                      const int* __restrict__ eid_s, float* __restrict__ out, int N) {
    const int c = threadIdx.x;  // 128 threads, one channel each
    __shared__ float4 se4[2][4][8];        // [buf][edge][8xfloat4 of eattr]
    float* sef = (float*)se4;
    // per-thread weight columns, pinned into VGPRs (asm defeats remat)
    float wfr[DDIM], wsr[DDIM];
#pragma unroll
    for (int d = 0; d < DDIM; d++) wfr[d] = WfeT[c * DDIM + d];
#pragma unroll
    for (int d = 0; d < DDIM; d++) wsr[d] = WseT[c * DDIM + d];
#pragma unroll
    for (int d = 0; d < DDIM; d++) {
        asm("" : "+v"(wfr[d]));
        asm("" : "+v"(wsr[d]));
    }
    const int jrow = c >> 5, jd = c & 31;  // staging role: 32 threads per edge row
    for (int i = blockIdx.x; i < N; i += gridDim.x) {
        const int e0 = rowptr[i], e1 = rowptr[i + 1];
        const float2 PRi = PR[(size_t)i * CDIM + c];
        float acc = 0.f;
        int cur = 0;
        if (e0 < e1) {
            int e = e0 + jrow; if (e >= e1) e = e1 - 1;
            sef[c] = eattr[(size_t)eid_s[e] * DDIM + jd];
        }
        for (int base = e0; base < e1; base += 4) {
            __syncthreads();
            if (base + 4 < e1) {  // stage next batch into other buffer
                int e = base + 4 + jrow; if (e >= e1) e = e1 - 1;
                sef[(cur ^ 1) * 128 + c] = eattr[(size_t)eid_s[e] * DDIM + jd];
            }
            const int m = min(4, e1 - base);
            float xf[4], xs[4];
#pragma unroll
            for (int j = 0; j < 4; j++) {
                int e = base + j; if (e >= e1) e = e1 - 1;
                float2 qs = QS[(size_t)src_s[e] * CDIM + c];
                xf[j] = PRi.x + qs.x;
                xs[j] = PRi.y + qs.y;
            }
#pragma unroll
            for (int db = 0; db < 8; db++) {
#pragma unroll
                for (int j = 0; j < 4; j++) {
                    float4 ev = se4[cur][j][db];
                    xf[j] = fmaf(ev.x, wfr[4 * db + 0], xf[j]);
                    xf[j] = fmaf(ev.y, wfr[4 * db + 1], xf[j]);
                    xf[j] = fmaf(ev.z, wfr[4 * db + 2], xf[j]);
                    xf[j] = fmaf(ev.w, wfr[4 * db + 3], xf[j]);
                    xs[j] = fmaf(ev.x, wsr[4 * db + 0], xs[j]);
                    xs[j] = fmaf(ev.y, wsr[4 * db + 1], xs[j]);
                    xs[j] = fmaf(ev.z, wsr[4 * db + 2], xs[j]);
                    xs[j] = fmaf(ev.w, wsr[4 * db + 3], xs[j]);
                }
            }
#pragma unroll
            for (int j = 0; j < 4; j++)
                if (j < m) acc = fmaf(sigm(xf[j]), softp(xs[j]), acc);
            cur ^= 1;
        }
        // Barrier before the next node's prologue staging: without this, a thread
        // that has finished this node can overwrite buffer 0 while slower threads
        // are still reading it (last batch reads buf 0 when batch count is odd).
        __syncthreads();
        float v = h[(size_t)i * CDIM + c] + acc;
        if (LEAKY) v = lrelu(v);
        out[(size_t)i * CDIM + c] = v;
    }
}

// ---------------- group boundaries (batch sorted) ----------------
__global__ void k_gbound(const int* __restrict__ batch, int* __restrict__ gstart,
                         int N, int G) {
    int g = threadIdx.x;
    if (g > G) return;
    int lo = 0, hi = N;
    while (lo < hi) {
        int mid = (lo + hi) >> 1;
        if (batch[mid] < g) lo = mid + 1; else hi = mid;
    }
    gstart[g] = lo;
}

// ---------------- fused mean-pool + MLP head ----------------
__global__ void k_poolhead(const float* __restrict__ h2, const int* __restrict__ gstart,
                           const int* __restrict__ y, const float* __restrict__ fc1W,
                           const float* __restrict__ fc1b, const float* __restrict__ fc2W,
                           const float* __restrict__ fc2b, float* __restrict__ out) {
    __shared__ float pooled[CDIM];
    int g = blockIdx.x;
    int c = threadIdx.x;  // 128 threads
    int n0 = gstart[g], n1 = gstart[g + 1];
    float acc = 0.f;
    for (int n = n0; n < n1; n++) acc += h2[(size_t)n * CDIM + c];
    float inv = 1.f / fmaxf((float)(n1 - n0), 1.f);
    pooled[c] = acc * inv;
    __syncthreads();
    float t = 0.f;
    if (c < 32) {
        t = fc1b[c];
        if (n1 > n0) t += fc1W[(CDIM + y[g]) * 32 + c];  // one-hot part of pooled
        for (int k = 0; k < CDIM; k++) t = fmaf(pooled[k], fc1W[k * 32 + c], t);
        t = lrelu(t) * fc2W[c];
    }
#pragma unroll
    for (int off = 16; off > 0; off >>= 1) t += __shfl_down(t, off, 64);
    if (c == 0) out[g] = sigm(t + fc2b[0]);
}

// ---------------- launch ----------------
extern "C" void kernel_launch(void* const* d_in, const int* in_sizes, int n_in,
                              void* d_out, int out_size, void* d_ws, size_t ws_size,
                              hipStream_t stream) {
    const float* x = (const float*)d_in[0];
    const int* y = (const int*)d_in[1];
    const int* ei = (const int*)d_in[2];
    const float* eattr = (const float*)d_in[3];
    const int* batch = (const int*)d_in[4];
    const float* lin_W = (const float*)d_in[5];
    const float* lin_b = (const float*)d_in[6];
    const float* c1_Wf = (const float*)d_in[7];
    const float* c1_bf = (const float*)d_in[8];
    const float* c1_Ws = (const float*)d_in[9];
    const float* c1_bs = (const float*)d_in[10];
    const float* c2_Wf = (const float*)d_in[11];
    const float* c2_bf = (const float*)d_in[12];
    const float* c2_Ws = (const float*)d_in[13];
    const float* c2_bs = (const float*)d_in[14];
    const float* fc1_W = (const float*)d_in[15];
    const float* fc1_b = (const float*)d_in[16];
    const float* fc2_W = (const float*)d_in[17];
    const float* fc2_b = (const float*)d_in[18];
    float* out = (float*)d_out;

    const int N = in_sizes[0] / CDIM;   // 50000
    const int E = in_sizes[2] / 2;      // 800000
    const int G = in_sizes[1];          // 64
    const int NB = (N + 255) / 256;

    // workspace carve-up (256B aligned)
    char* ws = (char*)d_ws;
    size_t off = 0;
    auto alloc = [&](size_t bytes) {
        size_t p = off;
        off = (off + bytes + 255) & ~(size_t)255;
        return (void*)(ws + p);
    };
    float* h0 = (float*)alloc((size_t)N * CDIM * 4);
    float* h1 = (float*)alloc((size_t)N * CDIM * 4);
    float2* PR = (float2*)alloc((size_t)N * CDIM * 8);
    float2* QS = (float2*)alloc((size_t)N * CDIM * 8);
    int* rowptr = (int*)alloc((size_t)(N + 1) * 4);
    int* counts = (int*)alloc((size_t)N * 4);
    int* cur = (int*)alloc((size_t)N * 4);
    int* bsum = (int*)alloc((size_t)NB * 4);
    int* boff = (int*)alloc((size_t)NB * 4);
    int* src_s = (int*)alloc((size_t)E * 4);
    int* eid_s = (int*)alloc((size_t)E * 4);
    int* gstart = (int*)alloc((size_t)(G + 1) * 4);
    // transposed weights
    float* w1fd = (float*)alloc((size_t)CDIM * CDIM * 4);
    float* w1fs = (float*)alloc((size_t)CDIM * CDIM * 4);
    float* w1fe = (float*)alloc((size_t)CDIM * DDIM * 4);
    float* w1sd = (float*)alloc((size_t)CDIM * CDIM * 4);
    float* w1ss = (float*)alloc((size_t)CDIM * CDIM * 4);
    float* w1se = (float*)alloc((size_t)CDIM * DDIM * 4);
    float* w2fd = (float*)alloc((size_t)CDIM * CDIM * 4);
    float* w2fs = (float*)alloc((size_t)CDIM * CDIM * 4);
    float* w2fe = (float*)alloc((size_t)CDIM * DDIM * 4);
    float* w2sd = (float*)alloc((size_t)CDIM * CDIM * 4);
    float* w2ss = (float*)alloc((size_t)CDIM * CDIM * 4);
    float* w2se = (float*)alloc((size_t)CDIM * DDIM * 4);
    float* wlT = (float*)alloc((size_t)CDIM * CDIM * 4);

    hipMemsetAsync(counts, 0, (size_t)N * 4, stream);

    // CSR (counting sort by dst)
    k_hist<<<4096, 256, 0, stream>>>(ei, counts, E);
    k_scan1<<<NB, 256, 0, stream>>>(counts, rowptr, bsum, N);
    k_scan2<<<1, 256, 0, stream>>>(bsum, boff, rowptr + N, NB);
    k_scan3<<<(N + 255) / 256, 256, 0, stream>>>(rowptr, cur, boff, N);
    k_fill<<<4096, 256, 0, stream>>>(ei, cur, src_s, eid_s, E);
    k_gbound<<<1, 128, 0, stream>>>(batch, gstart, N, G);
    k_wtc<<<(288 * CDIM + 255) / 256, 256, 0, stream>>>(c1_Wf, c1_Ws, w1fd, w1fs, w1fe,
                                                        w1sd, w1ss, w1se);
    k_wtc<<<(288 * CDIM + 255) / 256, 256, 0, stream>>>(c2_Wf, c2_Ws, w2fd, w2fs, w2fe,
                                                        w2sd, w2ss, w2se);
    k_wtl<<<(CDIM * CDIM + 255) / 256, 256, 0, stream>>>(lin_W, wlT);

    // layer 1
    k_lin1<32><<<(N + 31) / 32, CDIM, 0, stream>>>(x, y, batch, (const float4*)wlT, lin_W,
                                                   lin_b, h0, N);

    // conv1: h1 = leaky(h0 + agg1)
    k_gemm4<16><<<N / 16, CDIM, 0, stream>>>(h0, (const float4*)w1fd, (const float4*)w1fs,
                                             (const float4*)w1sd, (const float4*)w1ss,
                                             c1_bf, c1_bs, PR, QS, N);
    k_agg<1><<<4096, CDIM, 0, stream>>>(h0, PR, QS, eattr, w1fe, w1se, rowptr, src_s,
                                        eid_s, h1, N);

    // conv2: h2 = h1 + agg2 (into h0 buffer)
    k_gemm4<16><<<N / 16, CDIM, 0, stream>>>(h1, (const float4*)w2fd, (const float4*)w2fs,
                                             (const float4*)w2sd, (const float4*)w2ss,
                                             c2_bf, c2_bs, PR, QS, N);
    k_agg<0><<<4096, CDIM, 0, stream>>>(h1, PR, QS, eattr, w2fe, w2se, rowptr, src_s,
                                        eid_s, h0, N);

    // pool + head
    k_poolhead<<<G, CDIM, 0, stream>>>(h0, gstart, y, fc1_W, fc1_b, fc2_W, fc2_b, out);
}